// Round 4
// baseline (532.644 us; speedup 1.0000x reference)
//
#include <hip/hip_runtime.h>
#include <hip/hip_bf16.h>
#include <stdint.h>

#define BATCH 32
#define CDIM  256
#define NPIX  4096
#define HEADS 8
#define KD    64
#define VD    64
#define OQ    512     // HEADS*KD

typedef __hip_bfloat16 bf16;
typedef __attribute__((ext_vector_type(8))) short bf16x8;   // MFMA A/B fragment (4 VGPRs)
typedef __attribute__((ext_vector_type(4))) float floatx4;  // MFMA C/D fragment

union pack8 { bf16 h[8]; uint4 u; };

__device__ inline uint4 cvt8(const float* __restrict__ s) {
  float4 f0 = *reinterpret_cast<const float4*>(s);
  float4 f1 = *reinterpret_cast<const float4*>(s + 4);
  pack8 t;
  t.h[0] = __float2bfloat16(f0.x); t.h[1] = __float2bfloat16(f0.y);
  t.h[2] = __float2bfloat16(f0.z); t.h[3] = __float2bfloat16(f0.w);
  t.h[4] = __float2bfloat16(f1.x); t.h[5] = __float2bfloat16(f1.y);
  t.h[6] = __float2bfloat16(f1.z); t.h[7] = __float2bfloat16(f1.w);
  return t.u;
}

// ---------------------------------------------------------------------------
// Kernel T: x (b,C,N) fp32 -> xT (b,N,C) bf16, 64x64 tiles through LDS
// ---------------------------------------------------------------------------
__global__ __launch_bounds__(256) void transpose_k(const float* __restrict__ x,
                                                   bf16* __restrict__ xT) {
  __shared__ bf16 t[64 * 72];
  const int tid = threadIdx.x;
  const int b = blockIdx.z;
  const int n0 = blockIdx.x * 64;
  const int c0 = blockIdx.y * 64;
  const float* xb = x + (size_t)b * CDIM * NPIX;
  for (int p = 0; p < 2; ++p) {
    int cl = p * 32 + (tid >> 3);
    int no = (tid & 7) * 8;
    *reinterpret_cast<uint4*>(&t[cl * 72 + no]) =
        cvt8(xb + (size_t)(c0 + cl) * NPIX + n0 + no);
  }
  __syncthreads();
  bf16* xTb = xT + (size_t)b * NPIX * CDIM;
  for (int p = 0; p < 2; ++p) {
    int nl = p * 32 + (tid >> 3);
    int co = (tid & 7) * 8;
    pack8 tmp;
    for (int j = 0; j < 8; ++j) tmp.h[j] = t[(co + j) * 72 + nl];
    *reinterpret_cast<uint4*>(xTb + (size_t)(n0 + nl) * CDIM + c0 + co) = tmp.u;
  }
}

// ---------------------------------------------------------------------------
// Kernel G1: qkvT = xT (4096x256,bf16) * W^T (fp32->bf16)  -> (4096 x 640)
//   cols 0..511: q + fused softmax over each 64-col head group -> qT (bf16)
//   cols 512..575: k -> kT ; cols 576..639: v -> vT   (n-major, bf16)
// ---------------------------------------------------------------------------
__global__ __launch_bounds__(256, 2) void gemm_qkv(
    const bf16* __restrict__ xT,
    const float* __restrict__ Wq, const float* __restrict__ bq,
    const float* __restrict__ Wk, const float* __restrict__ bk,
    const float* __restrict__ Wv, const float* __restrict__ bv,
    bf16* __restrict__ qT, bf16* __restrict__ kT, bf16* __restrict__ vT) {
  __shared__ bf16 lsA[128 * 72];
  __shared__ bf16 lsB[128 * 72];
  const int tid = threadIdx.x;
  const int b  = blockIdx.z;
  const int bm = blockIdx.x;   // n-tile (M dim): 0..31
  const int ot = blockIdx.y;   // o-tile (N dim): 0..4
  const int lane = tid & 63;
  const int w    = tid >> 6;
  const int wm = w & 1, wn = w >> 1;
  const int l15 = lane & 15, quad = lane >> 4;

  const bf16* Ab = xT + (size_t)b * NPIX * CDIM + (size_t)bm * 128 * CDIM;

  floatx4 acc[4][4];
  const floatx4 zf = {0.f, 0.f, 0.f, 0.f};
  for (int i = 0; i < 4; ++i)
    for (int j = 0; j < 4; ++j) acc[i][j] = zf;

  for (int kb = 0; kb < CDIM / 64; ++kb) {
    __syncthreads();
    for (int ci = tid; ci < 1024; ci += 256) {          // stage A: 128 x 64 bf16
      int row = ci >> 3, off = (ci & 7) << 3;
      uint4 v = *reinterpret_cast<const uint4*>(Ab + (size_t)row * CDIM + kb * 64 + off);
      *reinterpret_cast<uint4*>(&lsA[row * 72 + off]) = v;
    }
    for (int ci = tid; ci < 1024; ci += 256) {          // stage B^T rows = o (fp32->bf16)
      int row = ci >> 3, off = (ci & 7) << 3;
      int o = ot * 128 + row;
      const float* src = (o < 512) ? (Wq + (size_t)o * CDIM)
                        : (o < 576) ? (Wk + (size_t)(o - 512) * CDIM)
                                    : (Wv + (size_t)(o - 576) * CDIM);
      *reinterpret_cast<uint4*>(&lsB[row * 72 + off]) = cvt8(src + kb * 64 + off);
    }
    __syncthreads();
    for (int kk = 0; kk < 64; kk += 32) {
      bf16x8 af[4], bfr[4];
      for (int mi = 0; mi < 4; ++mi)
        af[mi] = *reinterpret_cast<const bf16x8*>(&lsA[(wm * 64 + mi * 16 + l15) * 72 + kk + quad * 8]);
      for (int ni = 0; ni < 4; ++ni)
        bfr[ni] = *reinterpret_cast<const bf16x8*>(&lsB[(wn * 64 + ni * 16 + l15) * 72 + kk + quad * 8]);
      for (int mi = 0; mi < 4; ++mi)
        for (int ni = 0; ni < 4; ++ni)
          acc[mi][ni] = __builtin_amdgcn_mfma_f32_16x16x32_bf16(af[mi], bfr[ni], acc[mi][ni], 0, 0, 0);
    }
  }
  __syncthreads();

  // epilogue: this wave owns 64 rows (n) x 64 cols (o); reuse staging LDS
  bf16* ep = ((w < 2) ? lsA : lsB) + (w & 1) * (64 * 72);
  const int obase = ot * 128 + wn * 64;

  if (obase < 512) {   // q head group: softmax over the 64 cols, per row
    float bias[4];
    for (int ni = 0; ni < 4; ++ni) bias[ni] = bq[obase + ni * 16 + l15];
    for (int mi = 0; mi < 4; ++mi) {
      for (int r = 0; r < 4; ++r) {
        float v0 = acc[mi][0][r] + bias[0];
        float v1 = acc[mi][1][r] + bias[1];
        float v2 = acc[mi][2][r] + bias[2];
        float v3 = acc[mi][3][r] + bias[3];
        float m = fmaxf(fmaxf(v0, v1), fmaxf(v2, v3));
        for (int off = 1; off < 16; off <<= 1) m = fmaxf(m, __shfl_xor(m, off));
        float e0 = __expf(v0 - m), e1 = __expf(v1 - m);
        float e2 = __expf(v2 - m), e3 = __expf(v3 - m);
        float s = e0 + e1 + e2 + e3;
        for (int off = 1; off < 16; off <<= 1) s += __shfl_xor(s, off);
        float inv = 1.0f / s;
        int lr = mi * 16 + quad * 4 + r;
        ep[lr * 72 +  0 + l15] = __float2bfloat16(e0 * inv);
        ep[lr * 72 + 16 + l15] = __float2bfloat16(e1 * inv);
        ep[lr * 72 + 32 + l15] = __float2bfloat16(e2 * inv);
        ep[lr * 72 + 48 + l15] = __float2bfloat16(e3 * inv);
      }
    }
  } else {             // k (wn==0) or v (wn==1): bias add, raw write
    const float* bp = (wn == 0) ? bk : bv;
    float bias[4];
    for (int ni = 0; ni < 4; ++ni) bias[ni] = bp[ni * 16 + l15];
    for (int mi = 0; mi < 4; ++mi)
      for (int r = 0; r < 4; ++r) {
        int lr = mi * 16 + quad * 4 + r;
        for (int ni = 0; ni < 4; ++ni)
          ep[lr * 72 + ni * 16 + l15] = __float2bfloat16(acc[mi][ni][r] + bias[ni]);
      }
  }
  __syncthreads();

  // cooperative coalesced copy-out of this wave's 64x64 region
  bf16* dst; int rstride;
  const int row0 = bm * 128 + wm * 64;
  if (obase < 512)      { dst = qT + (size_t)b * NPIX * OQ + (size_t)row0 * OQ + obase; rstride = OQ; }
  else if (obase == 512){ dst = kT + (size_t)b * NPIX * KD + (size_t)row0 * KD;         rstride = KD; }
  else                  { dst = vT + (size_t)b * NPIX * VD + (size_t)row0 * VD;         rstride = VD; }
  for (int p = 0; p < 8; ++p) {
    int lr = (lane >> 3) + p * 8;
    int co = (lane & 7) * 8;
    uint4 v = *reinterpret_cast<const uint4*>(&ep[lr * 72 + co]);
    *reinterpret_cast<uint4*>(dst + (size_t)lr * rstride + co) = v;
  }
}

// ---------------------------------------------------------------------------
// Kernel CTX: ctx_num[b][d][e] = sum_n exp(k[d,n]) * v[e,n] ; denom[b][d]
//   (softmax shift skipped: k ~ N(0,1), exp is fp32-safe; shift-invariant)
// ---------------------------------------------------------------------------
__global__ __launch_bounds__(256) void ctx_partial(const bf16* __restrict__ kT,
                                                   const bf16* __restrict__ vT,
                                                   float* __restrict__ ctxn,
                                                   float* __restrict__ dnm) {
  __shared__ float ek[16 * 68];
  __shared__ float vv[16 * 68];
  const int tid = threadIdx.x;
  const int b = blockIdx.y, ci = blockIdx.x;
  const int dg = tid >> 4, eg = tid & 15;
  float acc[4][4] = {};
  float dloc = 0.f;
  for (int nb = 0; nb < 16; ++nb) {
    const int n0 = ci * 256 + nb * 16;
    __syncthreads();
    if (tid < 128) {
      int r = tid >> 3, off = (tid & 7) * 8;
      const bf16* src = kT + (size_t)b * NPIX * KD + (size_t)(n0 + r) * KD + off;
      for (int j = 0; j < 8; ++j) ek[r * 68 + off + j] = __expf(__bfloat162float(src[j]));
    } else {
      int t2 = tid - 128;
      int r = t2 >> 3, off = (t2 & 7) * 8;
      const bf16* src = vT + (size_t)b * NPIX * VD + (size_t)(n0 + r) * VD + off;
      for (int j = 0; j < 8; ++j) vv[r * 68 + off + j] = __bfloat162float(src[j]);
    }
    __syncthreads();
    for (int nn = 0; nn < 16; ++nn) {
      float4 e4 = *reinterpret_cast<const float4*>(&ek[nn * 68 + dg * 4]);
      float4 v4 = *reinterpret_cast<const float4*>(&vv[nn * 68 + eg * 4]);
      acc[0][0] += e4.x * v4.x; acc[0][1] += e4.x * v4.y; acc[0][2] += e4.x * v4.z; acc[0][3] += e4.x * v4.w;
      acc[1][0] += e4.y * v4.x; acc[1][1] += e4.y * v4.y; acc[1][2] += e4.y * v4.z; acc[1][3] += e4.y * v4.w;
      acc[2][0] += e4.z * v4.x; acc[2][1] += e4.z * v4.y; acc[2][2] += e4.z * v4.z; acc[2][3] += e4.z * v4.w;
      acc[3][0] += e4.w * v4.x; acc[3][1] += e4.w * v4.y; acc[3][2] += e4.w * v4.z; acc[3][3] += e4.w * v4.w;
    }
    if (tid < 64) {
      for (int nn = 0; nn < 16; ++nn) dloc += ek[nn * 68 + tid];
    }
  }
  for (int i = 0; i < 4; ++i)
    for (int j = 0; j < 4; ++j)
      atomicAdd(&ctxn[(size_t)b * 4096 + (dg * 4 + i) * 64 + eg * 4 + j], acc[i][j]);
  if (tid < 64) atomicAdd(&dnm[b * 64 + tid], dloc);
}

// ---------------------------------------------------------------------------
// Kernel MBUILD: M[b][c][h*64+d] = sum_e Wo[c][h*64+e] * ctx[d][e]/denom[d]
// ---------------------------------------------------------------------------
__global__ __launch_bounds__(256) void mbuild(const float* __restrict__ ctxn,
                                              const float* __restrict__ dnm,
                                              const float* __restrict__ Wo,
                                              bf16* __restrict__ Mm) {
  __shared__ float cn[64 * 68];
  const int h = blockIdx.x, b = blockIdx.y, tid = threadIdx.x;
  for (int ii = tid; ii < 4096; ii += 256) {
    int d = ii >> 6;
    cn[d * 68 + (ii & 63)] = ctxn[(size_t)b * 4096 + ii] / dnm[b * 64 + d];
  }
  __syncthreads();
  const int c = tid;
  const float* wrow = Wo + (size_t)c * OQ + h * 64;
  float wv[64];
  for (int e = 0; e < 64; ++e) wv[e] = wrow[e];
  bf16* mrow = Mm + (size_t)b * CDIM * OQ + (size_t)c * OQ + h * 64;
  for (int d = 0; d < 64; ++d) {
    float a = 0.f;
    for (int e = 0; e < 64; ++e) a += wv[e] * cn[d * 68 + e];
    mrow[d] = __float2bfloat16(a);
  }
}

// ---------------------------------------------------------------------------
// Kernel G2: y[b] (256x4096, fp32) = M_b (256x512) * q_smT^T + bo -> d_out
// ---------------------------------------------------------------------------
__global__ __launch_bounds__(256, 2) void gemm_out(
    const bf16* __restrict__ Mm, const bf16* __restrict__ qT,
    const float* __restrict__ bo, float* __restrict__ out) {
  __shared__ bf16 lsA[128 * 72];
  __shared__ bf16 lsB[128 * 72];
  const int tid = threadIdx.x;
  const int b  = blockIdx.z;
  const int cm = blockIdx.x;   // c-tile: 0..1
  const int nt = blockIdx.y;   // n-tile: 0..31
  const int lane = tid & 63;
  const int w    = tid >> 6;
  const int wm = w & 1, wn = w >> 1;
  const int l15 = lane & 15, quad = lane >> 4;

  const bf16* Ab = Mm + (size_t)b * CDIM * OQ + (size_t)cm * 128 * OQ;
  const bf16* Bb = qT + (size_t)b * NPIX * OQ + (size_t)nt * 128 * OQ;

  floatx4 acc[4][4];
  const floatx4 zf = {0.f, 0.f, 0.f, 0.f};
  for (int i = 0; i < 4; ++i)
    for (int j = 0; j < 4; ++j) acc[i][j] = zf;

  for (int kb = 0; kb < OQ / 64; ++kb) {
    __syncthreads();
    for (int ci = tid; ci < 1024; ci += 256) {
      int row = ci >> 3, off = (ci & 7) << 3;
      uint4 v = *reinterpret_cast<const uint4*>(Ab + (size_t)row * OQ + kb * 64 + off);
      *reinterpret_cast<uint4*>(&lsA[row * 72 + off]) = v;
    }
    for (int ci = tid; ci < 1024; ci += 256) {
      int row = ci >> 3, off = (ci & 7) << 3;
      uint4 v = *reinterpret_cast<const uint4*>(Bb + (size_t)row * OQ + kb * 64 + off);
      *reinterpret_cast<uint4*>(&lsB[row * 72 + off]) = v;
    }
    __syncthreads();
    for (int kk = 0; kk < 64; kk += 32) {
      bf16x8 af[4], bfr[4];
      for (int mi = 0; mi < 4; ++mi)
        af[mi] = *reinterpret_cast<const bf16x8*>(&lsA[(wm * 64 + mi * 16 + l15) * 72 + kk + quad * 8]);
      for (int ni = 0; ni < 4; ++ni)
        bfr[ni] = *reinterpret_cast<const bf16x8*>(&lsB[(wn * 64 + ni * 16 + l15) * 72 + kk + quad * 8]);
      for (int mi = 0; mi < 4; ++mi)
        for (int ni = 0; ni < 4; ++ni)
          acc[mi][ni] = __builtin_amdgcn_mfma_f32_16x16x32_bf16(af[mi], bfr[ni], acc[mi][ni], 0, 0, 0);
    }
  }

  // epilogue: direct fp32 stores (rows = c with stride NPIX, cols = n)
  const int row0 = cm * 128 + wm * 64;
  const int col0 = nt * 128 + wn * 64;
  float* outb = out + (size_t)b * CDIM * NPIX;
  for (int mi = 0; mi < 4; ++mi)
    for (int r = 0; r < 4; ++r) {
      int c = row0 + mi * 16 + quad * 4 + r;
      float bias = bo[c];
      float* orow = outb + (size_t)c * NPIX + col0;
      for (int ni = 0; ni < 4; ++ni)
        orow[ni * 16 + l15] = acc[mi][ni][r] + bias;
    }
}

// ---------------------------------------------------------------------------
// Host: adapt chunk size to ws_size (7,618,816 B scratch per batch).
// ---------------------------------------------------------------------------
extern "C" void kernel_launch(void* const* d_in, const int* in_sizes, int n_in,
                              void* d_out, int out_size, void* d_ws, size_t ws_size,
                              hipStream_t stream) {
  const float* x  = (const float*)d_in[0];
  const float* Wq = (const float*)d_in[1];
  const float* bq = (const float*)d_in[2];
  const float* Wk = (const float*)d_in[3];
  const float* bk = (const float*)d_in[4];
  const float* Wv = (const float*)d_in[5];
  const float* bv = (const float*)d_in[6];
  const float* Wo = (const float*)d_in[7];
  const float* bo = (const float*)d_in[8];
  float* out = (float*)d_out;

  const size_t pb_xT  = (size_t)NPIX * CDIM * 2;   // 2,097,152
  const size_t pb_qT  = (size_t)NPIX * OQ * 2;     // 4,194,304
  const size_t pb_kT  = (size_t)NPIX * KD * 2;     //   524,288
  const size_t pb_vT  = (size_t)NPIX * VD * 2;     //   524,288
  const size_t pb_ctx = (size_t)KD * VD * 4;       //    16,384
  const size_t pb_dnm = (size_t)KD * 4;            //       256
  const size_t pb_Mm  = (size_t)CDIM * OQ * 2;     //   262,144
  const size_t perB = pb_xT + pb_qT + pb_kT + pb_vT + pb_ctx + pb_dnm + pb_Mm;

  int CB = 32;
  while (CB > 1 && (size_t)CB * perB > ws_size) CB >>= 1;

  char* ws = (char*)d_ws;
  bf16*  xT   = (bf16*)ws;                                  ws += (size_t)CB * pb_xT;
  bf16*  qT   = (bf16*)ws;                                  ws += (size_t)CB * pb_qT;
  bf16*  kT   = (bf16*)ws;                                  ws += (size_t)CB * pb_kT;
  bf16*  vT   = (bf16*)ws;                                  ws += (size_t)CB * pb_vT;
  float* ctxn = (float*)ws;                                 ws += (size_t)CB * pb_ctx;
  float* dnm  = (float*)ws;                                 ws += (size_t)CB * pb_dnm;
  bf16*  Mm   = (bf16*)ws;

  for (int b0 = 0; b0 < BATCH; b0 += CB) {
    const float* x_c  = x   + (size_t)b0 * CDIM * NPIX;
    float*      out_c = out + (size_t)b0 * CDIM * NPIX;
    // zero the atomic accumulators (ctxn + dnm are contiguous)
    hipMemsetAsync(ctxn, 0, (size_t)CB * (pb_ctx + pb_dnm), stream);
    transpose_k<<<dim3(64, 4, CB), 256, 0, stream>>>(x_c, xT);
    gemm_qkv<<<dim3(32, 5, CB), 256, 0, stream>>>(xT, Wq, bq, Wk, bk, Wv, bv, qT, kT, vT);
    ctx_partial<<<dim3(16, CB), 256, 0, stream>>>(kT, vT, ctxn, dnm);
    mbuild<<<dim3(HEADS, CB), 256, 0, stream>>>(ctxn, dnm, Wo, Mm);
    gemm_out<<<dim3(2, 32, CB), 256, 0, stream>>>(Mm, qT, bo, out_c);
  }
}